// Round 9
// baseline (611.723 us; speedup 1.0000x reference)
//
#include <hip/hip_runtime.h>

#define NN 40000
#define NE 640000
#define HID 128
#define SCAN_BLK ((NN + 255) / 256)   // 157

typedef __attribute__((ext_vector_type(8)))  short short8;
typedef __attribute__((ext_vector_type(4)))  short short4v;
typedef __attribute__((ext_vector_type(16))) float floatx16;
typedef unsigned int uint;

__device__ __forceinline__ short f2bf(float f) {
    union { float f; unsigned u; } c; c.f = f;
    unsigned u = c.u;
    unsigned r = (u + 0x7FFF + ((u >> 16) & 1)) >> 16;   // RNE
    return (short)r;
}
__device__ __forceinline__ float bf2f(short h) {
    union { unsigned u; float f; } c;
    c.u = ((unsigned)(unsigned short)h) << 16;
    return c.f;
}
__device__ __forceinline__ float asf(uint u) {
    union { uint u; float f; } c; c.u = u; return c.f;
}
// Packed split-bf16: u32 = (hi_bf16 << 16) | lo_bf16; hi+lo ~ x to ~2^-17 rel.
__device__ __forceinline__ uint packsplit(float f) {
    short h = f2bf(f);
    short l = f2bf(f - bf2f(h));
    return ((uint)(unsigned short)h << 16) | (uint)(unsigned short)l;
}
__device__ __forceinline__ float unpackf(uint u) {
    return asf(u & 0xFFFF0000u) + asf(u << 16);
}
// 8 packed uints (two uint4) -> hi-plane short8 + lo-plane short8
__device__ __forceinline__ void unpack8(uint4 a, uint4 b, short8* h, short8* l) {
    short8 H, L;
    H[0] = (short)(a.x >> 16); L[0] = (short)a.x;
    H[1] = (short)(a.y >> 16); L[1] = (short)a.y;
    H[2] = (short)(a.z >> 16); L[2] = (short)a.z;
    H[3] = (short)(a.w >> 16); L[3] = (short)a.w;
    H[4] = (short)(b.x >> 16); L[4] = (short)b.x;
    H[5] = (short)(b.y >> 16); L[5] = (short)b.y;
    H[6] = (short)(b.z >> 16); L[6] = (short)b.z;
    H[7] = (short)(b.w >> 16); L[7] = (short)b.w;
    *h = H; *l = L;
}

// W fragment swizzle: element (o, k) of a [128][WS] row-major weight ->
// fragment-ordered index so a wave's B-load is base + lane*8 uints (coalesced).
// B frag for mfma_32x32x16: col=m31 (o&31), k = s*64 + kc*16 + half*8 + j.
__device__ __forceinline__ int wswz(int o, int k) {
    int s = k >> 6, kc = (k >> 4) & 3, half = (k >> 3) & 1, j = k & 7;
    int ct = o >> 5, m31 = o & 31;
    int lane = half * 32 + m31;
    return ((((s * 4 + kc) * 4 + ct) * 64 + lane) * 8 + j);
}

// ---------------- split-bf16 MFMA linear: A via LDS, W direct (swizzled) ----
// out[N][128] = relu?( X · W^T + b ). X = PHASES blocks of 128 packed cols
// (X0, X1), row stride 128; Wq = packed weights in wswz fragment order.
// acc += xh*wh + xl*wh + xh*wl (fp32 accum) -> fp32-grade result.
// Block: 256 thr = 4 waves; tile 128 rows x 128 cols; BK=64 per k-stage.
// Wave w owns rows [w*32, w*32+32), all 128 cols (4 accumulators).
// In-place safe (out==X0): all X reads precede the final barrier.
template<int PHASES, bool RELU>
__global__ __launch_bounds__(256, 4) void mfma_lin_kernel(
    const uint* __restrict__ X0, const uint* __restrict__ X1,
    const uint* __restrict__ Wq, const float* __restrict__ b,
    uint* __restrict__ out)
{
    constexpr int LDK = 76;                  // 64 + 12 shorts: 2-way-only banks
    __shared__ short sAh[128 * LDK];
    __shared__ short sAl[128 * LDK];

    const int t    = threadIdx.x;
    const int wave = t >> 6;
    const int lane = t & 63;
    const int m31  = lane & 31;
    const int half = lane >> 5;
    const int r0   = blockIdx.x * 128;

    floatx16 acc[4];
    #pragma unroll
    for (int ct = 0; ct < 4; ++ct)
        #pragma unroll
        for (int i = 0; i < 16; ++i) acc[ct][i] = 0.f;

    const int aOff = (wave * 32 + m31) * LDK + half * 8;

    for (int s = 0; s < 2 * PHASES; ++s) {   // k-stages of 64
        const int p   = s >> 1;
        const int xc0 = (s & 1) * 64;        // col offset within X row
        const uint* Xp = (PHASES == 2 && p == 1) ? X1 : X0;

        // stage A: 128 rows x 64 packed cols (2048 uint4, 8/thread)
        #pragma unroll
        for (int i = 0; i < 8; ++i) {
            int v   = t + 256 * i;
            int row = v >> 4;
            int c4  = (v & 15) * 4;
            int gr  = r0 + row;
            uint4 u = make_uint4(0u, 0u, 0u, 0u);
            if (gr < NN) u = *(const uint4*)(Xp + (size_t)gr * 128 + xc0 + c4);
            short4v hi, lo;
            hi.x = (short)(u.x >> 16); lo.x = (short)u.x;
            hi.y = (short)(u.y >> 16); lo.y = (short)u.y;
            hi.z = (short)(u.z >> 16); lo.z = (short)u.z;
            hi.w = (short)(u.w >> 16); lo.w = (short)u.w;
            *(short4v*)(sAh + row * LDK + c4) = hi;
            *(short4v*)(sAl + row * LDK + c4) = lo;
        }
        __syncthreads();

        #pragma unroll
        for (int kc = 0; kc < 4; ++kc) {     // 4 x K16
            short8 ah = *(const short8*)(sAh + aOff + kc * 16);
            short8 al = *(const short8*)(sAl + aOff + kc * 16);
            #pragma unroll
            for (int ct = 0; ct < 4; ++ct) {
                const uint* wr = Wq + ((((s * 4 + kc) * 4 + ct) * 64 + lane) * 8);
                uint4 w0 = *(const uint4*)(wr);
                uint4 w1 = *(const uint4*)(wr + 4);
                short8 bh, bl;
                unpack8(w0, w1, &bh, &bl);
                acc[ct] = __builtin_amdgcn_mfma_f32_32x32x16_bf16(ah, bh, acc[ct], 0, 0, 0);
                acc[ct] = __builtin_amdgcn_mfma_f32_32x32x16_bf16(al, bh, acc[ct], 0, 0, 0);
                acc[ct] = __builtin_amdgcn_mfma_f32_32x32x16_bf16(ah, bl, acc[ct], 0, 0, 0);
            }
        }
        __syncthreads();                     // guard LDS restage / in-place
    }

    // epilogue: bias + relu + pack + store.
    // C/D: col=lane&31, row=(reg&3)+8*(reg>>2)+4*half
    #pragma unroll
    for (int ct = 0; ct < 4; ++ct) {
        const int col = ct * 32 + m31;
        const float bias = b[col];
        #pragma unroll
        for (int reg = 0; reg < 16; ++reg) {
            int row = (reg & 3) + 8 * (reg >> 2) + 4 * half;
            int gr  = r0 + wave * 32 + row;
            if (gr < NN) {
                float v = acc[ct][reg] + bias;
                if (RELU) v = fmaxf(v, 0.f);
                out[(size_t)gr * HID + col] = packsplit(v);
            }
        }
    }
}

// ---------------- fp32 linear for K=11 (first embed only), packs output ----
template<int K, bool RELU>
__global__ __launch_bounds__(128) void lin_kernel(
    const float* __restrict__ X, const float* __restrict__ W,
    const float* __restrict__ b, uint* __restrict__ out, int n_rows)
{
    constexpr int ROWS = 8;
    __shared__ float xs[ROWS * K];
    const int m  = threadIdx.x;
    const int r0 = blockIdx.x * ROWS;
    for (int i = threadIdx.x; i < ROWS * K; i += 128) {
        int r = i / K, k = i - r * K;
        int row = r0 + r;
        xs[i] = (row < n_rows) ? X[(size_t)row * K + k] : 0.f;
    }
    __syncthreads();
    float acc[ROWS] = {};
    const float* Wm = W + (size_t)m * K;
    for (int k = 0; k < K; ++k) {
        float w = Wm[k];
        #pragma unroll
        for (int r = 0; r < ROWS; ++r) acc[r] += xs[r * K + k] * w;
    }
    const float bias = b[m];
    #pragma unroll
    for (int r = 0; r < ROWS; ++r) {
        int row = r0 + r;
        if (row < n_rows) {
            float v = acc[r] + bias;
            if (RELU) v = fmaxf(v, 0.f);
            out[(size_t)row * HID + m] = packsplit(v);
        }
    }
}

// ---------------- weight pre-split+swizzle (once per launch, 131072 elems) --
__global__ __launch_bounds__(256) void wprep_kernel(
    const float* __restrict__ w0, const float* __restrict__ w1,
    const float* __restrict__ w2, const float* __restrict__ w3,
    const float* __restrict__ w4, const float* __restrict__ w5,
    uint* __restrict__ wp)
{
    int i = blockIdx.x * 256 + threadIdx.x;
    if (i >= 131072) return;
    const float* src; int off, ws;
    if      (i < 16384)  { src = w0; off = 0;      ws = 128; }
    else if (i < 49152)  { src = w1; off = 16384;  ws = 256; }
    else if (i < 65536)  { src = w2; off = 49152;  ws = 128; }
    else if (i < 81920)  { src = w3; off = 65536;  ws = 128; }
    else if (i < 114688) { src = w4; off = 81920;  ws = 256; }
    else                 { src = w5; off = 114688; ws = 128; }
    int L = i - off;
    int o = L / ws, k = L - o * ws;
    wp[off + wswz(o, k)] = packsplit(src[L]);
}

// ---------------- CSR build (by dst) ----------------
__global__ __launch_bounds__(256) void hist_kernel(
    const int* __restrict__ dst, int* __restrict__ cnt)
{
    int e = blockIdx.x * 256 + threadIdx.x;
    if (e < NE) atomicAdd(&cnt[dst[e]], 1);
}

__global__ __launch_bounds__(256) void scan1_kernel(
    const int* __restrict__ cnt, int* __restrict__ row_ptr,
    int* __restrict__ partials)
{
    __shared__ int s[256];
    const int t = threadIdx.x;
    const int i = blockIdx.x * 256 + t;
    int v = (i < NN) ? cnt[i] : 0;
    s[t] = v;
    __syncthreads();
    #pragma unroll
    for (int off = 1; off < 256; off <<= 1) {
        int x = (t >= off) ? s[t - off] : 0;
        __syncthreads();
        s[t] += x;
        __syncthreads();
    }
    if (i < NN) row_ptr[i] = s[t] - v;
    if (t == 255) partials[blockIdx.x] = s[255];
}

__global__ __launch_bounds__(256) void scan2_kernel(
    int* __restrict__ partials, int* __restrict__ row_ptr)
{
    __shared__ int s[256];
    const int t = threadIdx.x;
    int v = (t < SCAN_BLK) ? partials[t] : 0;
    s[t] = v;
    __syncthreads();
    #pragma unroll
    for (int off = 1; off < 256; off <<= 1) {
        int x = (t >= off) ? s[t - off] : 0;
        __syncthreads();
        s[t] += x;
        __syncthreads();
    }
    if (t < SCAN_BLK) partials[t] = s[t] - v;
    if (t == 255) row_ptr[NN] = s[255];
}

__global__ __launch_bounds__(256) void scan3_kernel(
    int* __restrict__ row_ptr, const int* __restrict__ partials)
{
    const int i = blockIdx.x * 256 + threadIdx.x;
    if (i < NN) row_ptr[i] += partials[blockIdx.x];
}

__global__ __launch_bounds__(256) void fill_kernel(
    const int* __restrict__ src, const int* __restrict__ dst,
    const int* __restrict__ row_ptr, int* __restrict__ pos,
    int* __restrict__ esrc)
{
    int e = blockIdx.x * 256 + threadIdx.x;
    if (e >= NE) return;
    int d = dst[e];
    int p = row_ptr[d] + atomicAdd(&pos[d], 1);
    esrc[p] = src[e];
}

// ---------------- Gather aggregation (packed in/out, unroll x4) -------------
#define ACCUM(u, H, L)                                           \
    H.x += asf(u.x & 0xFFFF0000u); L.x += asf(u.x << 16);        \
    H.y += asf(u.y & 0xFFFF0000u); L.y += asf(u.y << 16);        \
    H.z += asf(u.z & 0xFFFF0000u); L.z += asf(u.z << 16);        \
    H.w += asf(u.w & 0xFFFF0000u); L.w += asf(u.w << 16);

__global__ __launch_bounds__(256) void gather_agg_kernel(
    const uint* __restrict__ h, const int* __restrict__ row_ptr,
    const int* __restrict__ esrc, uint* __restrict__ agg)
{
    int t = blockIdx.x * 256 + threadIdx.x;
    int node = t >> 5;
    int c4   = t & 31;
    if (node >= NN) return;
    const int lo = row_ptr[node], hi = row_ptr[node + 1];
    float4 aH = make_float4(0,0,0,0), aL = make_float4(0,0,0,0);
    float4 bH = make_float4(0,0,0,0), bL = make_float4(0,0,0,0);
    float4 cH = make_float4(0,0,0,0), cL = make_float4(0,0,0,0);
    float4 dH = make_float4(0,0,0,0), dL = make_float4(0,0,0,0);
    int e = lo;
    for (; e + 4 <= hi; e += 4) {
        int s0 = esrc[e], s1 = esrc[e+1], s2 = esrc[e+2], s3 = esrc[e+3];
        uint4 u0 = *(const uint4*)(h + (size_t)s0 * HID + c4 * 4);
        uint4 u1 = *(const uint4*)(h + (size_t)s1 * HID + c4 * 4);
        uint4 u2 = *(const uint4*)(h + (size_t)s2 * HID + c4 * 4);
        uint4 u3 = *(const uint4*)(h + (size_t)s3 * HID + c4 * 4);
        ACCUM(u0, aH, aL); ACCUM(u1, bH, bL);
        ACCUM(u2, cH, cL); ACCUM(u3, dH, dL);
    }
    for (; e < hi; ++e) {
        int s0 = esrc[e];
        uint4 u0 = *(const uint4*)(h + (size_t)s0 * HID + c4 * 4);
        ACCUM(u0, aH, aL);
    }
    uint4 o;
    o.x = packsplit((aH.x + bH.x) + (cH.x + dH.x) + (aL.x + bL.x) + (cL.x + dL.x));
    o.y = packsplit((aH.y + bH.y) + (cH.y + dH.y) + (aL.y + bL.y) + (cL.y + dL.y));
    o.z = packsplit((aH.z + bH.z) + (cH.z + dH.z) + (aL.z + bL.z) + (cL.z + dL.z));
    o.w = packsplit((aH.w + bH.w) + (cH.w + dH.w) + (aL.w + bL.w) + (cL.w + dL.w));
    *(uint4*)(agg + (size_t)node * HID + c4 * 4) = o;
}

// ---------------- Head ----------------
__global__ __launch_bounds__(256) void head_out_kernel(
    const uint* __restrict__ h, const float* __restrict__ w,
    const float* __restrict__ b, float* __restrict__ out)
{
    long long t = (long long)blockIdx.x * blockDim.x + threadIdx.x;
    int node = (int)(t >> 6);
    int lane = threadIdx.x & 63;
    if (node >= NN) return;
    const uint* hr = h + (size_t)node * HID;
    float a = unpackf(hr[lane]) * w[lane] + unpackf(hr[64 + lane]) * w[64 + lane];
    #pragma unroll
    for (int off = 32; off > 0; off >>= 1) a += __shfl_down(a, off);
    if (lane == 0) out[node] = a + b[0];
}

extern "C" void kernel_launch(void* const* d_in, const int* in_sizes, int n_in,
                              void* d_out, int out_size, void* d_ws, size_t ws_size,
                              hipStream_t stream)
{
    const float* x     = (const float*)d_in[0];
    const int*   eidx  = (const int*)d_in[1];
    const float* c0_w1 = (const float*)d_in[2],  *c0_b1 = (const float*)d_in[3];
    const float* c0_w2 = (const float*)d_in[4],  *c0_b2 = (const float*)d_in[5];
    const float* c0_w3 = (const float*)d_in[6],  *c0_b3 = (const float*)d_in[7];
    const float* c1_w1 = (const float*)d_in[8],  *c1_b1 = (const float*)d_in[9];
    const float* c1_w2 = (const float*)d_in[10], *c1_b2 = (const float*)d_in[11];
    const float* c1_w3 = (const float*)d_in[12], *c1_b3 = (const float*)d_in[13];
    const float* f_w1  = (const float*)d_in[14], *f_b1  = (const float*)d_in[15];
    const float* f_w2  = (const float*)d_in[16], *f_b2  = (const float*)d_in[17];
    const int* src = eidx;
    const int* dst = eidx + NE;
    float* out = (float*)d_out;

    const size_t BUF = (size_t)NN * HID;
    uint* bA = (uint*)d_ws;
    uint* bB = bA + BUF;
    uint* bC = bB + BUF;
    int* row_ptr  = (int*)(bC + BUF);        // NN+1
    int* cnt      = row_ptr + (NN + 1);      // NN (reused as fill cursor)
    int* esrc     = cnt + NN;                // NE
    int* partials = esrc + NE;               // SCAN_BLK
    uint* wp      = (uint*)(partials + SCAN_BLK);  // 131072 packed+swizzled W

    // packed-weight offsets in wp
    uint* p_c0w2 = wp + 0;
    uint* p_c0w3 = wp + 16384;
    uint* p_c1w1 = wp + 49152;
    uint* p_c1w2 = wp + 65536;
    uint* p_c1w3 = wp + 81920;
    uint* p_fw1  = wp + 114688;

    const int nb8  = (NN + 7) / 8;            // 5000 (K=11 lin)
    const int nbm  = (NN + 127) / 128;        // 313 (mfma lin)
    const int eb   = (NE + 255) / 256;        // 2500
    const int gb   = (NN * 32 + 255) / 256;   // 5000
    const int hb   = (NN * 64 + 255) / 256;   // 10000

    // ---- weight prep + CSR build ----
    wprep_kernel<<<512, 256, 0, stream>>>(c0_w2, c0_w3, c1_w1, c1_w2, c1_w3, f_w1, wp);
    (void)hipMemsetAsync(cnt, 0, NN * sizeof(int), stream);
    hist_kernel<<<eb, 256, 0, stream>>>(dst, cnt);
    scan1_kernel<<<SCAN_BLK, 256, 0, stream>>>(cnt, row_ptr, partials);
    scan2_kernel<<<1, 256, 0, stream>>>(partials, row_ptr);
    scan3_kernel<<<SCAN_BLK, 256, 0, stream>>>(row_ptr, partials);
    (void)hipMemsetAsync(cnt, 0, NN * sizeof(int), stream);
    fill_kernel<<<eb, 256, 0, stream>>>(src, dst, row_ptr, cnt, esrc);

    // ---- conv0 ----
    lin_kernel<11, true><<<nb8, 128, 0, stream>>>(x, c0_w1, c0_b1, bA, NN);
    gather_agg_kernel<<<gb, 256, 0, stream>>>(bA, row_ptr, esrc, bB);
    mfma_lin_kernel<1, true><<<nbm, 256, 0, stream>>>(bB, nullptr, p_c0w2, c0_b2, bB);
    gather_agg_kernel<<<gb, 256, 0, stream>>>(bB, row_ptr, esrc, bC);
    mfma_lin_kernel<1, true><<<nbm, 256, 0, stream>>>(bC, nullptr, p_c0w2, c0_b2, bC);
    mfma_lin_kernel<2, false><<<nbm, 256, 0, stream>>>(bB, bC, p_c0w3, c0_b3, bA);

    // ---- conv1 ----
    mfma_lin_kernel<1, true><<<nbm, 256, 0, stream>>>(bA, nullptr, p_c1w1, c1_b1, bA);
    gather_agg_kernel<<<gb, 256, 0, stream>>>(bA, row_ptr, esrc, bB);
    mfma_lin_kernel<1, true><<<nbm, 256, 0, stream>>>(bB, nullptr, p_c1w2, c1_b2, bB);
    gather_agg_kernel<<<gb, 256, 0, stream>>>(bB, row_ptr, esrc, bC);
    mfma_lin_kernel<1, true><<<nbm, 256, 0, stream>>>(bC, nullptr, p_c1w2, c1_b2, bC);
    mfma_lin_kernel<2, false><<<nbm, 256, 0, stream>>>(bB, bC, p_c1w3, c1_b3, bA);

    // ---- head ----
    mfma_lin_kernel<1, true><<<nbm, 256, 0, stream>>>(bA, nullptr, p_fw1, f_b1, bA);
    head_out_kernel<<<hb, 256, 0, stream>>>(bA, f_w2, f_b2, out);
}

// Round 10
// 422.026 us; speedup vs baseline: 1.4495x; 1.4495x over previous
//
#include <hip/hip_runtime.h>

#define NN 40000
#define NE 640000
#define HID 128
#define SCAN_BLK ((NN + 255) / 256)   // 157

typedef __attribute__((ext_vector_type(8)))  short short8;
typedef __attribute__((ext_vector_type(4)))  short short4v;
typedef __attribute__((ext_vector_type(16))) float floatx16;
typedef unsigned int uint;

__device__ __forceinline__ short f2bf(float f) {
    union { float f; unsigned u; } c; c.f = f;
    unsigned u = c.u;
    unsigned r = (u + 0x7FFF + ((u >> 16) & 1)) >> 16;   // RNE
    return (short)r;
}
__device__ __forceinline__ float bf2f(short h) {
    union { unsigned u; float f; } c;
    c.u = ((unsigned)(unsigned short)h) << 16;
    return c.f;
}
__device__ __forceinline__ float asf(uint u) {
    union { uint u; float f; } c; c.u = u; return c.f;
}
// Packed split-bf16: u32 = (hi_bf16 << 16) | lo_bf16; hi+lo ~ x to ~2^-17 rel.
__device__ __forceinline__ uint packsplit(float f) {
    short h = f2bf(f);
    short l = f2bf(f - bf2f(h));
    return ((uint)(unsigned short)h << 16) | (uint)(unsigned short)l;
}
__device__ __forceinline__ float unpackf(uint u) {
    return asf(u & 0xFFFF0000u) + asf(u << 16);
}
// 8 packed uints (two uint4) -> hi-plane short8 + lo-plane short8
__device__ __forceinline__ void unpack8(uint4 a, uint4 b, short8* h, short8* l) {
    short8 H, L;
    H[0] = (short)(a.x >> 16); L[0] = (short)a.x;
    H[1] = (short)(a.y >> 16); L[1] = (short)a.y;
    H[2] = (short)(a.z >> 16); L[2] = (short)a.z;
    H[3] = (short)(a.w >> 16); L[3] = (short)a.w;
    H[4] = (short)(b.x >> 16); L[4] = (short)b.x;
    H[5] = (short)(b.y >> 16); L[5] = (short)b.y;
    H[6] = (short)(b.z >> 16); L[6] = (short)b.z;
    H[7] = (short)(b.w >> 16); L[7] = (short)b.w;
    *h = H; *l = L;
}

// W fragment swizzle (verified on HW in round 9): element (o, k) of a
// [128][WS] row-major weight -> index so a wave's B-load is base+lane*8 uints.
// chunk = k>>4, half = (k>>3)&1, ct = o>>5 (== wave), lane = half*32 + (o&31).
__device__ __forceinline__ int wswz(int o, int k) {
    int chunk = k >> 4, half = (k >> 3) & 1, j = k & 7;
    int ct = o >> 5, m31 = o & 31;
    int lane = half * 32 + m31;
    return (((chunk * 4 + ct) * 64 + lane) * 8 + j);
}

// A-fragment LDS layout for a 32-row tile: plane[(chunk*2+half)*256 + row*8 + j]
// GEMM-side read: lane (m31=row, half) -> base + lane-contiguous 16 B.

// ---------------- fused gather + split-bf16 MFMA linear -------------------
// out[n][:] = relu( W · (sum_{e: dst=n} h[src[e]]) + b ), 32 nodes per block.
// Phase 1: 4 passes x 8 nodes gather fp32 sums, split into LDS A-fragments.
// Phase 2: 4 waves, wave w -> output cols [32w,32w+32), W direct (swizzled).
__global__ __launch_bounds__(256, 4) void fused_gather_lin_kernel(
    const uint* __restrict__ h, const int* __restrict__ row_ptr,
    const int* __restrict__ esrc, const uint* __restrict__ Wq,
    const float* __restrict__ bias, uint* __restrict__ out)
{
    __shared__ short sAh[4096];
    __shared__ short sAl[4096];
    const int t  = threadIdx.x;
    const int r0 = blockIdx.x * 32;
    const int c4 = t & 31;               // 4-uint column group
    const int sub = c4 >> 1;             // k-subchunk of 8
    const int j0  = (c4 & 1) * 4;

    for (int p = 0; p < 4; ++p) {
        const int nl   = p * 8 + (t >> 5);
        const int node = r0 + nl;
        const int lo = row_ptr[node], hi = row_ptr[node + 1];
        float4 aH = make_float4(0,0,0,0), aL = make_float4(0,0,0,0);
        float4 bH = make_float4(0,0,0,0), bL = make_float4(0,0,0,0);
        float4 cH = make_float4(0,0,0,0), cL = make_float4(0,0,0,0);
        float4 dH = make_float4(0,0,0,0), dL = make_float4(0,0,0,0);
        int e = lo;
        for (; e + 4 <= hi; e += 4) {
            int s0 = esrc[e], s1 = esrc[e+1], s2 = esrc[e+2], s3 = esrc[e+3];
            uint4 u0 = *(const uint4*)(h + (size_t)s0 * HID + c4 * 4);
            uint4 u1 = *(const uint4*)(h + (size_t)s1 * HID + c4 * 4);
            uint4 u2 = *(const uint4*)(h + (size_t)s2 * HID + c4 * 4);
            uint4 u3 = *(const uint4*)(h + (size_t)s3 * HID + c4 * 4);
            aH.x += asf(u0.x & 0xFFFF0000u); aL.x += asf(u0.x << 16);
            aH.y += asf(u0.y & 0xFFFF0000u); aL.y += asf(u0.y << 16);
            aH.z += asf(u0.z & 0xFFFF0000u); aL.z += asf(u0.z << 16);
            aH.w += asf(u0.w & 0xFFFF0000u); aL.w += asf(u0.w << 16);
            bH.x += asf(u1.x & 0xFFFF0000u); bL.x += asf(u1.x << 16);
            bH.y += asf(u1.y & 0xFFFF0000u); bL.y += asf(u1.y << 16);
            bH.z += asf(u1.z & 0xFFFF0000u); bL.z += asf(u1.z << 16);
            bH.w += asf(u1.w & 0xFFFF0000u); bL.w += asf(u1.w << 16);
            cH.x += asf(u2.x & 0xFFFF0000u); cL.x += asf(u2.x << 16);
            cH.y += asf(u2.y & 0xFFFF0000u); cL.y += asf(u2.y << 16);
            cH.z += asf(u2.z & 0xFFFF0000u); cL.z += asf(u2.z << 16);
            cH.w += asf(u2.w & 0xFFFF0000u); cL.w += asf(u2.w << 16);
            dH.x += asf(u3.x & 0xFFFF0000u); dL.x += asf(u3.x << 16);
            dH.y += asf(u3.y & 0xFFFF0000u); dL.y += asf(u3.y << 16);
            dH.z += asf(u3.z & 0xFFFF0000u); dL.z += asf(u3.z << 16);
            dH.w += asf(u3.w & 0xFFFF0000u); dL.w += asf(u3.w << 16);
        }
        for (; e < hi; ++e) {
            int s0 = esrc[e];
            uint4 u0 = *(const uint4*)(h + (size_t)s0 * HID + c4 * 4);
            aH.x += asf(u0.x & 0xFFFF0000u); aL.x += asf(u0.x << 16);
            aH.y += asf(u0.y & 0xFFFF0000u); aL.y += asf(u0.y << 16);
            aH.z += asf(u0.z & 0xFFFF0000u); aL.z += asf(u0.z << 16);
            aH.w += asf(u0.w & 0xFFFF0000u); aL.w += asf(u0.w << 16);
        }
        float vx = (aH.x + bH.x) + (cH.x + dH.x) + (aL.x + bL.x) + (cL.x + dL.x);
        float vy = (aH.y + bH.y) + (cH.y + dH.y) + (aL.y + bL.y) + (cL.y + dL.y);
        float vz = (aH.z + bH.z) + (cH.z + dH.z) + (aL.z + bL.z) + (cL.z + dL.z);
        float vw = (aH.w + bH.w) + (cH.w + dH.w) + (aL.w + bL.w) + (cL.w + dL.w);
        short4v Hq, Lq;
        short hh;
        hh = f2bf(vx); Hq.x = hh; Lq.x = f2bf(vx - bf2f(hh));
        hh = f2bf(vy); Hq.y = hh; Lq.y = f2bf(vy - bf2f(hh));
        hh = f2bf(vz); Hq.z = hh; Lq.z = f2bf(vz - bf2f(hh));
        hh = f2bf(vw); Hq.w = hh; Lq.w = f2bf(vw - bf2f(hh));
        const int off = sub * 256 + nl * 8 + j0;
        *(short4v*)(sAh + off) = Hq;
        *(short4v*)(sAl + off) = Lq;
    }
    __syncthreads();

    // GEMM phase
    const int wv   = t >> 6;
    const int lane = t & 63;
    const int m31  = lane & 31;
    const int half = lane >> 5;
    floatx16 acc;
    #pragma unroll
    for (int i = 0; i < 16; ++i) acc[i] = 0.f;
    #pragma unroll
    for (int c = 0; c < 8; ++c) {
        short8 ah = *(const short8*)(sAh + (c * 2 + half) * 256 + m31 * 8);
        short8 al = *(const short8*)(sAl + (c * 2 + half) * 256 + m31 * 8);
        const uint* wr = Wq + ((size_t)(c * 4 + wv) * 64 + lane) * 8;
        uint4 w0 = *(const uint4*)(wr);
        uint4 w1 = *(const uint4*)(wr + 4);
        short8 bh, bl;
        unpack8(w0, w1, &bh, &bl);
        acc = __builtin_amdgcn_mfma_f32_32x32x16_bf16(ah, bh, acc, 0, 0, 0);
        acc = __builtin_amdgcn_mfma_f32_32x32x16_bf16(al, bh, acc, 0, 0, 0);
        acc = __builtin_amdgcn_mfma_f32_32x32x16_bf16(ah, bl, acc, 0, 0, 0);
    }
    const int col = wv * 32 + m31;
    const float bb = bias[col];
    #pragma unroll
    for (int reg = 0; reg < 16; ++reg) {
        int row = (reg & 3) + 8 * (reg >> 2) + 4 * half;
        float v = fmaxf(acc[reg] + bb, 0.f);
        out[(size_t)(r0 + row) * HID + col] = packsplit(v);
    }
}

// ---------------- standalone split-bf16 MFMA linear, 32-row tiles ----------
// out = relu?( [X0|X1] · W^T + b ); Wq swizzled packed. Never aliased.
template<int PHASES, bool RELU>
__global__ __launch_bounds__(256, 4) void lin32_kernel(
    const uint* __restrict__ X0, const uint* __restrict__ X1,
    const uint* __restrict__ Wq, const float* __restrict__ bias,
    uint* __restrict__ out)
{
    __shared__ short sAh[PHASES * 4096];
    __shared__ short sAl[PHASES * 4096];
    const int t  = threadIdx.x;
    const int r0 = blockIdx.x * 32;

    // stage: PHASES*1024 uint4, coalesced, into fragment-order LDS
    #pragma unroll
    for (int i = 0; i < PHASES * 4; ++i) {
        int v = t + 256 * i;
        const uint* Xp = (PHASES == 2 && v >= 1024) ? X1 : X0;
        int vv  = v & 1023;
        int row = vv >> 5, q = vv & 31;
        uint4 u = *(const uint4*)(Xp + (size_t)(r0 + row) * 128 + q * 4);
        int kk  = ((PHASES == 2) ? (v >> 10) * 128 : 0) + q * 4;
        int off = (kk >> 3) * 256 + row * 8 + (q & 1) * 4;
        short4v hi, lo;
        hi.x = (short)(u.x >> 16); lo.x = (short)u.x;
        hi.y = (short)(u.y >> 16); lo.y = (short)u.y;
        hi.z = (short)(u.z >> 16); lo.z = (short)u.z;
        hi.w = (short)(u.w >> 16); lo.w = (short)u.w;
        *(short4v*)(sAh + off) = hi;
        *(short4v*)(sAl + off) = lo;
    }
    __syncthreads();

    const int wv   = t >> 6;
    const int lane = t & 63;
    const int m31  = lane & 31;
    const int half = lane >> 5;
    floatx16 acc;
    #pragma unroll
    for (int i = 0; i < 16; ++i) acc[i] = 0.f;
    #pragma unroll
    for (int c = 0; c < PHASES * 8; ++c) {
        short8 ah = *(const short8*)(sAh + (c * 2 + half) * 256 + m31 * 8);
        short8 al = *(const short8*)(sAl + (c * 2 + half) * 256 + m31 * 8);
        const uint* wr = Wq + ((size_t)(c * 4 + wv) * 64 + lane) * 8;
        uint4 w0 = *(const uint4*)(wr);
        uint4 w1 = *(const uint4*)(wr + 4);
        short8 bh, bl;
        unpack8(w0, w1, &bh, &bl);
        acc = __builtin_amdgcn_mfma_f32_32x32x16_bf16(ah, bh, acc, 0, 0, 0);
        acc = __builtin_amdgcn_mfma_f32_32x32x16_bf16(al, bh, acc, 0, 0, 0);
        acc = __builtin_amdgcn_mfma_f32_32x32x16_bf16(ah, bl, acc, 0, 0, 0);
    }
    const int col = wv * 32 + m31;
    const float bb = bias[col];
    #pragma unroll
    for (int reg = 0; reg < 16; ++reg) {
        int row = (reg & 3) + 8 * (reg >> 2) + 4 * half;
        float v = acc[reg] + bb;
        if (RELU) v = fmaxf(v, 0.f);
        out[(size_t)(r0 + row) * HID + col] = packsplit(v);
    }
}

// ---------------- fp32 linear for K=11 (first embed only), packs output ----
template<int K, bool RELU>
__global__ __launch_bounds__(128) void lin_kernel(
    const float* __restrict__ X, const float* __restrict__ W,
    const float* __restrict__ b, uint* __restrict__ out, int n_rows)
{
    constexpr int ROWS = 8;
    __shared__ float xs[ROWS * K];
    const int m  = threadIdx.x;
    const int r0 = blockIdx.x * ROWS;
    for (int i = threadIdx.x; i < ROWS * K; i += 128) {
        int r = i / K, k = i - r * K;
        int row = r0 + r;
        xs[i] = (row < n_rows) ? X[(size_t)row * K + k] : 0.f;
    }
    __syncthreads();
    float acc[ROWS] = {};
    const float* Wm = W + (size_t)m * K;
    for (int k = 0; k < K; ++k) {
        float w = Wm[k];
        #pragma unroll
        for (int r = 0; r < ROWS; ++r) acc[r] += xs[r * K + k] * w;
    }
    const float bias = b[m];
    #pragma unroll
    for (int r = 0; r < ROWS; ++r) {
        int row = r0 + r;
        if (row < n_rows) {
            float v = acc[r] + bias;
            if (RELU) v = fmaxf(v, 0.f);
            out[(size_t)row * HID + m] = packsplit(v);
        }
    }
}

// ---------------- weight pre-split+swizzle (once per launch) ----------------
__global__ __launch_bounds__(256) void wprep_kernel(
    const float* __restrict__ w0, const float* __restrict__ w1,
    const float* __restrict__ w2, const float* __restrict__ w3,
    const float* __restrict__ w4, const float* __restrict__ w5,
    uint* __restrict__ wp)
{
    int i = blockIdx.x * 256 + threadIdx.x;
    if (i >= 131072) return;
    const float* src; int off, ws;
    if      (i < 16384)  { src = w0; off = 0;      ws = 128; }
    else if (i < 49152)  { src = w1; off = 16384;  ws = 256; }
    else if (i < 65536)  { src = w2; off = 49152;  ws = 128; }
    else if (i < 81920)  { src = w3; off = 65536;  ws = 128; }
    else if (i < 114688) { src = w4; off = 81920;  ws = 256; }
    else                 { src = w5; off = 114688; ws = 128; }
    int L = i - off;
    int o = L / ws, k = L - o * ws;
    wp[off + wswz(o, k)] = packsplit(src[L]);
}

// ---------------- CSR build (by dst) ----------------
__global__ __launch_bounds__(256) void hist_kernel(
    const int* __restrict__ dst, int* __restrict__ cnt)
{
    int e = blockIdx.x * 256 + threadIdx.x;
    if (e < NE) atomicAdd(&cnt[dst[e]], 1);
}

__global__ __launch_bounds__(256) void scan1_kernel(
    const int* __restrict__ cnt, int* __restrict__ row_ptr,
    int* __restrict__ partials)
{
    __shared__ int s[256];
    const int t = threadIdx.x;
    const int i = blockIdx.x * 256 + t;
    int v = (i < NN) ? cnt[i] : 0;
    s[t] = v;
    __syncthreads();
    #pragma unroll
    for (int off = 1; off < 256; off <<= 1) {
        int x = (t >= off) ? s[t - off] : 0;
        __syncthreads();
        s[t] += x;
        __syncthreads();
    }
    if (i < NN) row_ptr[i] = s[t] - v;
    if (t == 255) partials[blockIdx.x] = s[255];
}

__global__ __launch_bounds__(256) void scan2_kernel(
    int* __restrict__ partials, int* __restrict__ row_ptr)
{
    __shared__ int s[256];
    const int t = threadIdx.x;
    int v = (t < SCAN_BLK) ? partials[t] : 0;
    s[t] = v;
    __syncthreads();
    #pragma unroll
    for (int off = 1; off < 256; off <<= 1) {
        int x = (t >= off) ? s[t - off] : 0;
        __syncthreads();
        s[t] += x;
        __syncthreads();
    }
    if (t < SCAN_BLK) partials[t] = s[t] - v;
    if (t == 255) row_ptr[NN] = s[255];
}

__global__ __launch_bounds__(256) void scan3_kernel(
    int* __restrict__ row_ptr, const int* __restrict__ partials)
{
    const int i = blockIdx.x * 256 + threadIdx.x;
    if (i < NN) row_ptr[i] += partials[blockIdx.x];
}

__global__ __launch_bounds__(256) void fill_kernel(
    const int* __restrict__ src, const int* __restrict__ dst,
    const int* __restrict__ row_ptr, int* __restrict__ pos,
    int* __restrict__ esrc)
{
    int e = blockIdx.x * 256 + threadIdx.x;
    if (e >= NE) return;
    int d = dst[e];
    int p = row_ptr[d] + atomicAdd(&pos[d], 1);
    esrc[p] = src[e];
}

// ---------------- Head ----------------
__global__ __launch_bounds__(256) void head_out_kernel(
    const uint* __restrict__ h, const float* __restrict__ w,
    const float* __restrict__ b, float* __restrict__ out)
{
    long long t = (long long)blockIdx.x * blockDim.x + threadIdx.x;
    int node = (int)(t >> 6);
    int lane = threadIdx.x & 63;
    if (node >= NN) return;
    const uint* hr = h + (size_t)node * HID;
    float a = unpackf(hr[lane]) * w[lane] + unpackf(hr[64 + lane]) * w[64 + lane];
    #pragma unroll
    for (int off = 32; off > 0; off >>= 1) a += __shfl_down(a, off);
    if (lane == 0) out[node] = a + b[0];
}

extern "C" void kernel_launch(void* const* d_in, const int* in_sizes, int n_in,
                              void* d_out, int out_size, void* d_ws, size_t ws_size,
                              hipStream_t stream)
{
    const float* x     = (const float*)d_in[0];
    const int*   eidx  = (const int*)d_in[1];
    const float* c0_w1 = (const float*)d_in[2],  *c0_b1 = (const float*)d_in[3];
    const float* c0_w2 = (const float*)d_in[4],  *c0_b2 = (const float*)d_in[5];
    const float* c0_w3 = (const float*)d_in[6],  *c0_b3 = (const float*)d_in[7];
    const float* c1_w1 = (const float*)d_in[8],  *c1_b1 = (const float*)d_in[9];
    const float* c1_w2 = (const float*)d_in[10], *c1_b2 = (const float*)d_in[11];
    const float* c1_w3 = (const float*)d_in[12], *c1_b3 = (const float*)d_in[13];
    const float* f_w1  = (const float*)d_in[14], *f_b1  = (const float*)d_in[15];
    const float* f_w2  = (const float*)d_in[16], *f_b2  = (const float*)d_in[17];
    const int* src = eidx;
    const int* dst = eidx + NE;
    float* out = (float*)d_out;

    const size_t BUF = (size_t)NN * HID;
    uint* bA = (uint*)d_ws;
    uint* bB = bA + BUF;
    uint* bC = bB + BUF;
    int* row_ptr  = (int*)(bC + BUF);        // NN+1
    int* cnt      = row_ptr + (NN + 1);      // NN (reused as fill cursor)
    int* esrc     = cnt + NN;                // NE
    int* partials = esrc + NE;               // SCAN_BLK
    uint* wp      = (uint*)(partials + SCAN_BLK);  // 131072 packed+swizzled W

    uint* p_c0w2 = wp + 0;
    uint* p_c0w3 = wp + 16384;
    uint* p_c1w1 = wp + 49152;
    uint* p_c1w2 = wp + 65536;
    uint* p_c1w3 = wp + 81920;
    uint* p_fw1  = wp + 114688;

    const int nb8  = (NN + 7) / 8;            // 5000 (K=11 embed)
    const int nbl  = (NN + 31) / 32;          // 1250 (fused / lin32)
    const int eb   = (NE + 255) / 256;        // 2500
    const int hb   = (NN * 64 + 255) / 256;   // 10000

    // ---- weight prep + CSR build ----
    wprep_kernel<<<512, 256, 0, stream>>>(c0_w2, c0_w3, c1_w1, c1_w2, c1_w3, f_w1, wp);
    (void)hipMemsetAsync(cnt, 0, NN * sizeof(int), stream);
    hist_kernel<<<eb, 256, 0, stream>>>(dst, cnt);
    scan1_kernel<<<SCAN_BLK, 256, 0, stream>>>(cnt, row_ptr, partials);
    scan2_kernel<<<1, 256, 0, stream>>>(partials, row_ptr);
    scan3_kernel<<<SCAN_BLK, 256, 0, stream>>>(row_ptr, partials);
    (void)hipMemsetAsync(cnt, 0, NN * sizeof(int), stream);
    fill_kernel<<<eb, 256, 0, stream>>>(src, dst, row_ptr, cnt, esrc);

    // ---- conv0 ----
    lin_kernel<11, true><<<nb8, 128, 0, stream>>>(x, c0_w1, c0_b1, bA, NN);
    fused_gather_lin_kernel<<<nbl, 256, 0, stream>>>(bA, row_ptr, esrc, p_c0w2, c0_b2, bB); // l1
    fused_gather_lin_kernel<<<nbl, 256, 0, stream>>>(bB, row_ptr, esrc, p_c0w2, c0_b2, bC); // l2
    lin32_kernel<2, false><<<nbl, 256, 0, stream>>>(bB, bC, p_c0w3, c0_b3, bA);             // conv0 out

    // ---- conv1 ----
    lin32_kernel<1, true><<<nbl, 256, 0, stream>>>(bA, nullptr, p_c1w1, c1_b1, bB);         // h1
    fused_gather_lin_kernel<<<nbl, 256, 0, stream>>>(bB, row_ptr, esrc, p_c1w2, c1_b2, bC); // l1
    fused_gather_lin_kernel<<<nbl, 256, 0, stream>>>(bC, row_ptr, esrc, p_c1w2, c1_b2, bA); // l2
    lin32_kernel<2, false><<<nbl, 256, 0, stream>>>(bC, bA, p_c1w3, c1_b3, bB);             // conv1 out

    // ---- head ----
    lin32_kernel<1, true><<<nbl, 256, 0, stream>>>(bB, nullptr, p_fw1, f_b1, bC);
    head_out_kernel<<<hb, 256, 0, stream>>>(bC, f_w2, f_b2, out);
}

// Round 11
// 413.086 us; speedup vs baseline: 1.4809x; 1.0216x over previous
//
#include <hip/hip_runtime.h>

#define NN 40000
#define NE 640000
#define HID 128
#define SCAN_BLK ((NN + 255) / 256)   // 157

typedef __attribute__((ext_vector_type(8)))  short short8;
typedef __attribute__((ext_vector_type(4)))  short short4v;
typedef __attribute__((ext_vector_type(16))) float floatx16;
typedef unsigned int uint;

__device__ __forceinline__ short f2bf(float f) {
    union { float f; unsigned u; } c; c.f = f;
    unsigned u = c.u;
    unsigned r = (u + 0x7FFF + ((u >> 16) & 1)) >> 16;   // RNE
    return (short)r;
}
__device__ __forceinline__ float bf2f(short h) {
    union { unsigned u; float f; } c;
    c.u = ((unsigned)(unsigned short)h) << 16;
    return c.f;
}
__device__ __forceinline__ float asf(uint u) {
    union { uint u; float f; } c; c.u = u; return c.f;
}
// Packed split-bf16: u32 = (hi_bf16 << 16) | lo_bf16; hi+lo ~ x to ~2^-17 rel.
__device__ __forceinline__ uint packsplit(float f) {
    short h = f2bf(f);
    short l = f2bf(f - bf2f(h));
    return ((uint)(unsigned short)h << 16) | (uint)(unsigned short)l;
}
__device__ __forceinline__ float unpackf(uint u) {
    return asf(u & 0xFFFF0000u) + asf(u << 16);
}
__device__ __forceinline__ void unpack8(uint4 a, uint4 b, short8* h, short8* l) {
    short8 H, L;
    H[0] = (short)(a.x >> 16); L[0] = (short)a.x;
    H[1] = (short)(a.y >> 16); L[1] = (short)a.y;
    H[2] = (short)(a.z >> 16); L[2] = (short)a.z;
    H[3] = (short)(a.w >> 16); L[3] = (short)a.w;
    H[4] = (short)(b.x >> 16); L[4] = (short)b.x;
    H[5] = (short)(b.y >> 16); L[5] = (short)b.y;
    H[6] = (short)(b.z >> 16); L[6] = (short)b.z;
    H[7] = (short)(b.w >> 16); L[7] = (short)b.w;
    *h = H; *l = L;
}

// W fragment swizzle (HW-verified r9/r10): element (o,k) of [128][WS] row-major
// -> index so a wave's B-load is base + lane*8 uints (coalesced).
__device__ __forceinline__ int wswz(int o, int k) {
    int chunk = k >> 4, half = (k >> 3) & 1, j = k & 7;
    int ct = o >> 5, m31 = o & 31;
    int lane = half * 32 + m31;
    return (((chunk * 4 + ct) * 64 + lane) * 8 + j);
}

// ---------------- fused gather + split-bf16 MFMA linear (unchanged r10) ----
__global__ __launch_bounds__(256, 4) void fused_gather_lin_kernel(
    const uint* __restrict__ h, const int* __restrict__ row_ptr,
    const int* __restrict__ esrc, const uint* __restrict__ Wq,
    const float* __restrict__ bias, uint* __restrict__ out)
{
    __shared__ short sAh[4096];
    __shared__ short sAl[4096];
    const int t  = threadIdx.x;
    const int r0 = blockIdx.x * 32;
    const int c4 = t & 31;
    const int sub = c4 >> 1;
    const int j0  = (c4 & 1) * 4;

    for (int p = 0; p < 4; ++p) {
        const int nl   = p * 8 + (t >> 5);
        const int node = r0 + nl;
        const int lo = row_ptr[node], hi = row_ptr[node + 1];
        float4 aH = make_float4(0,0,0,0), aL = make_float4(0,0,0,0);
        float4 bH = make_float4(0,0,0,0), bL = make_float4(0,0,0,0);
        float4 cH = make_float4(0,0,0,0), cL = make_float4(0,0,0,0);
        float4 dH = make_float4(0,0,0,0), dL = make_float4(0,0,0,0);
        int e = lo;
        for (; e + 4 <= hi; e += 4) {
            int s0 = esrc[e], s1 = esrc[e+1], s2 = esrc[e+2], s3 = esrc[e+3];
            uint4 u0 = *(const uint4*)(h + (size_t)s0 * HID + c4 * 4);
            uint4 u1 = *(const uint4*)(h + (size_t)s1 * HID + c4 * 4);
            uint4 u2 = *(const uint4*)(h + (size_t)s2 * HID + c4 * 4);
            uint4 u3 = *(const uint4*)(h + (size_t)s3 * HID + c4 * 4);
            aH.x += asf(u0.x & 0xFFFF0000u); aL.x += asf(u0.x << 16);
            aH.y += asf(u0.y & 0xFFFF0000u); aL.y += asf(u0.y << 16);
            aH.z += asf(u0.z & 0xFFFF0000u); aL.z += asf(u0.z << 16);
            aH.w += asf(u0.w & 0xFFFF0000u); aL.w += asf(u0.w << 16);
            bH.x += asf(u1.x & 0xFFFF0000u); bL.x += asf(u1.x << 16);
            bH.y += asf(u1.y & 0xFFFF0000u); bL.y += asf(u1.y << 16);
            bH.z += asf(u1.z & 0xFFFF0000u); bL.z += asf(u1.z << 16);
            bH.w += asf(u1.w & 0xFFFF0000u); bL.w += asf(u1.w << 16);
            cH.x += asf(u2.x & 0xFFFF0000u); cL.x += asf(u2.x << 16);
            cH.y += asf(u2.y & 0xFFFF0000u); cL.y += asf(u2.y << 16);
            cH.z += asf(u2.z & 0xFFFF0000u); cL.z += asf(u2.z << 16);
            cH.w += asf(u2.w & 0xFFFF0000u); cL.w += asf(u2.w << 16);
            dH.x += asf(u3.x & 0xFFFF0000u); dL.x += asf(u3.x << 16);
            dH.y += asf(u3.y & 0xFFFF0000u); dL.y += asf(u3.y << 16);
            dH.z += asf(u3.z & 0xFFFF0000u); dL.z += asf(u3.z << 16);
            dH.w += asf(u3.w & 0xFFFF0000u); dL.w += asf(u3.w << 16);
        }
        for (; e < hi; ++e) {
            int s0 = esrc[e];
            uint4 u0 = *(const uint4*)(h + (size_t)s0 * HID + c4 * 4);
            aH.x += asf(u0.x & 0xFFFF0000u); aL.x += asf(u0.x << 16);
            aH.y += asf(u0.y & 0xFFFF0000u); aL.y += asf(u0.y << 16);
            aH.z += asf(u0.z & 0xFFFF0000u); aL.z += asf(u0.z << 16);
            aH.w += asf(u0.w & 0xFFFF0000u); aL.w += asf(u0.w << 16);
        }
        float vx = (aH.x + bH.x) + (cH.x + dH.x) + (aL.x + bL.x) + (cL.x + dL.x);
        float vy = (aH.y + bH.y) + (cH.y + dH.y) + (aL.y + bL.y) + (cL.y + dL.y);
        float vz = (aH.z + bH.z) + (cH.z + dH.z) + (aL.z + bL.z) + (cL.z + dL.z);
        float vw = (aH.w + bH.w) + (cH.w + dH.w) + (aL.w + bL.w) + (cL.w + dL.w);
        short4v Hq, Lq;
        short hh;
        hh = f2bf(vx); Hq.x = hh; Lq.x = f2bf(vx - bf2f(hh));
        hh = f2bf(vy); Hq.y = hh; Lq.y = f2bf(vy - bf2f(hh));
        hh = f2bf(vz); Hq.z = hh; Lq.z = f2bf(vz - bf2f(hh));
        hh = f2bf(vw); Hq.w = hh; Lq.w = f2bf(vw - bf2f(hh));
        const int off = sub * 256 + nl * 8 + j0;
        *(short4v*)(sAh + off) = Hq;
        *(short4v*)(sAl + off) = Lq;
    }
    __syncthreads();

    const int wv   = t >> 6;
    const int lane = t & 63;
    const int m31  = lane & 31;
    const int half = lane >> 5;
    floatx16 acc;
    #pragma unroll
    for (int i = 0; i < 16; ++i) acc[i] = 0.f;
    #pragma unroll
    for (int c = 0; c < 8; ++c) {
        short8 ah = *(const short8*)(sAh + (c * 2 + half) * 256 + m31 * 8);
        short8 al = *(const short8*)(sAl + (c * 2 + half) * 256 + m31 * 8);
        const uint* wr = Wq + ((size_t)(c * 4 + wv) * 64 + lane) * 8;
        uint4 w0 = *(const uint4*)(wr);
        uint4 w1 = *(const uint4*)(wr + 4);
        short8 bh, bl;
        unpack8(w0, w1, &bh, &bl);
        acc = __builtin_amdgcn_mfma_f32_32x32x16_bf16(ah, bh, acc, 0, 0, 0);
        acc = __builtin_amdgcn_mfma_f32_32x32x16_bf16(al, bh, acc, 0, 0, 0);
        acc = __builtin_amdgcn_mfma_f32_32x32x16_bf16(ah, bl, acc, 0, 0, 0);
    }
    const int col = wv * 32 + m31;
    const float bb = bias[col];
    #pragma unroll
    for (int reg = 0; reg < 16; ++reg) {
        int row = (reg & 3) + 8 * (reg >> 2) + 4 * half;
        float v = fmaxf(acc[reg] + bb, 0.f);
        out[(size_t)(r0 + row) * HID + col] = packsplit(v);
    }
}

// ---------------- standalone split-bf16 MFMA linear, 32-row tiles ----------
template<int PHASES, bool RELU>
__global__ __launch_bounds__(256, 4) void lin32_kernel(
    const uint* __restrict__ X0, const uint* __restrict__ X1,
    const uint* __restrict__ Wq, const float* __restrict__ bias,
    uint* __restrict__ out)
{
    __shared__ short sAh[PHASES * 4096];
    __shared__ short sAl[PHASES * 4096];
    const int t  = threadIdx.x;
    const int r0 = blockIdx.x * 32;

    #pragma unroll
    for (int i = 0; i < PHASES * 4; ++i) {
        int v = t + 256 * i;
        const uint* Xp = (PHASES == 2 && v >= 1024) ? X1 : X0;
        int vv  = v & 1023;
        int row = vv >> 5, q = vv & 31;
        uint4 u = *(const uint4*)(Xp + (size_t)(r0 + row) * 128 + q * 4);
        int kk  = ((PHASES == 2) ? (v >> 10) * 128 : 0) + q * 4;
        int off = (kk >> 3) * 256 + row * 8 + (q & 1) * 4;
        short4v hi, lo;
        hi.x = (short)(u.x >> 16); lo.x = (short)u.x;
        hi.y = (short)(u.y >> 16); lo.y = (short)u.y;
        hi.z = (short)(u.z >> 16); lo.z = (short)u.z;
        hi.w = (short)(u.w >> 16); lo.w = (short)u.w;
        *(short4v*)(sAh + off) = hi;
        *(short4v*)(sAl + off) = lo;
    }
    __syncthreads();

    const int wv   = t >> 6;
    const int lane = t & 63;
    const int m31  = lane & 31;
    const int half = lane >> 5;
    floatx16 acc;
    #pragma unroll
    for (int i = 0; i < 16; ++i) acc[i] = 0.f;
    #pragma unroll
    for (int c = 0; c < PHASES * 8; ++c) {
        short8 ah = *(const short8*)(sAh + (c * 2 + half) * 256 + m31 * 8);
        short8 al = *(const short8*)(sAl + (c * 2 + half) * 256 + m31 * 8);
        const uint* wr = Wq + ((size_t)(c * 4 + wv) * 64 + lane) * 8;
        uint4 w0 = *(const uint4*)(wr);
        uint4 w1 = *(const uint4*)(wr + 4);
        short8 bh, bl;
        unpack8(w0, w1, &bh, &bl);
        acc = __builtin_amdgcn_mfma_f32_32x32x16_bf16(ah, bh, acc, 0, 0, 0);
        acc = __builtin_amdgcn_mfma_f32_32x32x16_bf16(al, bh, acc, 0, 0, 0);
        acc = __builtin_amdgcn_mfma_f32_32x32x16_bf16(ah, bl, acc, 0, 0, 0);
    }
    const int col = wv * 32 + m31;
    const float bb = bias[col];
    #pragma unroll
    for (int reg = 0; reg < 16; ++reg) {
        int row = (reg & 3) + 8 * (reg >> 2) + 4 * half;
        float v = acc[reg] + bb;
        if (RELU) v = fmaxf(v, 0.f);
        out[(size_t)(r0 + row) * HID + col] = packsplit(v);
    }
}

// ---------------- cat-GEMM (Wb) + fused head: out[n] = f2·relu(Wb·cat+bb)+c -
// g = relu(Wb·[X0|X1] + bias) staged in LDS, then per-node dot with f2.
__global__ __launch_bounds__(256, 3) void cat_head_kernel(
    const uint* __restrict__ X0, const uint* __restrict__ X1,
    const uint* __restrict__ Wq, const float* __restrict__ bias,
    const float* __restrict__ f2, const float* __restrict__ f2b,
    float* __restrict__ out)
{
    __shared__ short sAh[8192];
    __shared__ short sAl[8192];
    __shared__ float gbuf[32 * 129];
    const int t  = threadIdx.x;
    const int r0 = blockIdx.x * 32;

    #pragma unroll
    for (int i = 0; i < 8; ++i) {
        int v = t + 256 * i;
        const uint* Xp = (v >= 1024) ? X1 : X0;
        int vv  = v & 1023;
        int row = vv >> 5, q = vv & 31;
        uint4 u = *(const uint4*)(Xp + (size_t)(r0 + row) * 128 + q * 4);
        int kk  = (v >> 10) * 128 + q * 4;
        int off = (kk >> 3) * 256 + row * 8 + (q & 1) * 4;
        short4v hi, lo;
        hi.x = (short)(u.x >> 16); lo.x = (short)u.x;
        hi.y = (short)(u.y >> 16); lo.y = (short)u.y;
        hi.z = (short)(u.z >> 16); lo.z = (short)u.z;
        hi.w = (short)(u.w >> 16); lo.w = (short)u.w;
        *(short4v*)(sAh + off) = hi;
        *(short4v*)(sAl + off) = lo;
    }
    __syncthreads();

    const int wv   = t >> 6;
    const int lane = t & 63;
    const int m31  = lane & 31;
    const int half = lane >> 5;
    floatx16 acc;
    #pragma unroll
    for (int i = 0; i < 16; ++i) acc[i] = 0.f;
    #pragma unroll
    for (int c = 0; c < 16; ++c) {
        short8 ah = *(const short8*)(sAh + (c * 2 + half) * 256 + m31 * 8);
        short8 al = *(const short8*)(sAl + (c * 2 + half) * 256 + m31 * 8);
        const uint* wr = Wq + ((size_t)(c * 4 + wv) * 64 + lane) * 8;
        uint4 w0 = *(const uint4*)(wr);
        uint4 w1 = *(const uint4*)(wr + 4);
        short8 bh, bl;
        unpack8(w0, w1, &bh, &bl);
        acc = __builtin_amdgcn_mfma_f32_32x32x16_bf16(ah, bh, acc, 0, 0, 0);
        acc = __builtin_amdgcn_mfma_f32_32x32x16_bf16(al, bh, acc, 0, 0, 0);
        acc = __builtin_amdgcn_mfma_f32_32x32x16_bf16(ah, bl, acc, 0, 0, 0);
    }
    const int col = wv * 32 + m31;
    const float bb = bias[col];
    #pragma unroll
    for (int reg = 0; reg < 16; ++reg) {
        int row = (reg & 3) + 8 * (reg >> 2) + 4 * half;
        gbuf[row * 129 + col] = fmaxf(acc[reg] + bb, 0.f);
    }
    __syncthreads();

    // head: node = t>>3, seg = t&7 -> 16 cols each, 8-lane shuffle reduce
    const int node = t >> 3;
    const int seg  = t & 7;
    const float* gr = gbuf + node * 129 + seg * 16;
    float a = 0.f;
    #pragma unroll
    for (int i = 0; i < 16; ++i) a += gr[i] * f2[seg * 16 + i];
    a += __shfl_down(a, 4, 8);
    a += __shfl_down(a, 2, 8);
    a += __shfl_down(a, 1, 8);
    if (seg == 0) out[r0 + node] = a + f2b[0];
}

// ---------------- fp32 linear for K=11 (first embed only), packs output ----
template<int K, bool RELU>
__global__ __launch_bounds__(128) void lin_kernel(
    const float* __restrict__ X, const float* __restrict__ W,
    const float* __restrict__ b, uint* __restrict__ out, int n_rows)
{
    constexpr int ROWS = 8;
    __shared__ float xs[ROWS * K];
    const int m  = threadIdx.x;
    const int r0 = blockIdx.x * ROWS;
    for (int i = threadIdx.x; i < ROWS * K; i += 128) {
        int r = i / K, k = i - r * K;
        int row = r0 + r;
        xs[i] = (row < n_rows) ? X[(size_t)row * K + k] : 0.f;
    }
    __syncthreads();
    float acc[ROWS] = {};
    const float* Wm = W + (size_t)m * K;
    for (int k = 0; k < K; ++k) {
        float w = Wm[k];
        #pragma unroll
        for (int r = 0; r < ROWS; ++r) acc[r] += xs[r * K + k] * w;
    }
    const float bias = b[m];
    #pragma unroll
    for (int r = 0; r < ROWS; ++r) {
        int row = r0 + r;
        if (row < n_rows) {
            float v = acc[r] + bias;
            if (RELU) v = fmaxf(v, 0.f);
            out[(size_t)row * HID + m] = packsplit(v);
        }
    }
}

// ---------------- weight prep: pack+swizzle c0_w2, c1_w2 -------------------
__global__ __launch_bounds__(256) void wprep_kernel(
    const float* __restrict__ w0, const float* __restrict__ w1,
    uint* __restrict__ wp)
{
    int i = blockIdx.x * 256 + threadIdx.x;
    if (i >= 32768) return;
    const float* src = (i < 16384) ? w0 : w1;
    int off = (i < 16384) ? 0 : 16384;
    int L = i - off;
    int o = L >> 7, k = L & 127;
    wp[off + wswz(o, k)] = packsplit(src[L]);
}

// ---------------- weight fold: Wq = swz(pack(A·B)), bias' = A·b_in + b_out --
// A [128][128], B [128][256] row-major. Grid 128 blocks x 256 thr: o=blk, k=thr.
__global__ __launch_bounds__(256) void wfold_kernel(
    const float* __restrict__ A, const float* __restrict__ B,
    const float* __restrict__ b_in, const float* __restrict__ b_out,
    uint* __restrict__ outWq, float* __restrict__ outBias)
{
    const int o = blockIdx.x;
    const int k = threadIdx.x;
    const float* Ar = A + o * 128;
    float s = 0.f;
    for (int j = 0; j < 128; ++j) s += Ar[j] * B[j * 256 + k];
    outWq[wswz(o, k)] = packsplit(s);
    if (k == 0) {
        float sb = 0.f;
        for (int j = 0; j < 128; ++j) sb += Ar[j] * b_in[j];
        outBias[o] = sb + b_out[o];
    }
}

// ---------------- CSR build (by dst) ----------------
__global__ __launch_bounds__(256) void hist_kernel(
    const int* __restrict__ dst, int* __restrict__ cnt)
{
    int e = blockIdx.x * 256 + threadIdx.x;
    if (e < NE) atomicAdd(&cnt[dst[e]], 1);
}

__global__ __launch_bounds__(256) void scan1_kernel(
    const int* __restrict__ cnt, int* __restrict__ row_ptr,
    int* __restrict__ partials)
{
    __shared__ int s[256];
    const int t = threadIdx.x;
    const int i = blockIdx.x * 256 + t;
    int v = (i < NN) ? cnt[i] : 0;
    s[t] = v;
    __syncthreads();
    #pragma unroll
    for (int off = 1; off < 256; off <<= 1) {
        int x = (t >= off) ? s[t - off] : 0;
        __syncthreads();
        s[t] += x;
        __syncthreads();
    }
    if (i < NN) row_ptr[i] = s[t] - v;
    if (t == 255) partials[blockIdx.x] = s[255];
}

__global__ __launch_bounds__(256) void scan2_kernel(
    int* __restrict__ partials, int* __restrict__ row_ptr)
{
    __shared__ int s[256];
    const int t = threadIdx.x;
    int v = (t < SCAN_BLK) ? partials[t] : 0;
    s[t] = v;
    __syncthreads();
    #pragma unroll
    for (int off = 1; off < 256; off <<= 1) {
        int x = (t >= off) ? s[t - off] : 0;
        __syncthreads();
        s[t] += x;
        __syncthreads();
    }
    if (t < SCAN_BLK) partials[t] = s[t] - v;
    if (t == 255) row_ptr[NN] = s[255];
}

__global__ __launch_bounds__(256) void scan3_kernel(
    int* __restrict__ row_ptr, const int* __restrict__ partials)
{
    const int i = blockIdx.x * 256 + threadIdx.x;
    if (i < NN) row_ptr[i] += partials[blockIdx.x];
}

__global__ __launch_bounds__(256) void fill_kernel(
    const int* __restrict__ src, const int* __restrict__ dst,
    const int* __restrict__ row_ptr, int* __restrict__ pos,
    int* __restrict__ esrc)
{
    int e = blockIdx.x * 256 + threadIdx.x;
    if (e >= NE) return;
    int d = dst[e];
    int p = row_ptr[d] + atomicAdd(&pos[d], 1);
    esrc[p] = src[e];
}

extern "C" void kernel_launch(void* const* d_in, const int* in_sizes, int n_in,
                              void* d_out, int out_size, void* d_ws, size_t ws_size,
                              hipStream_t stream)
{
    const float* x     = (const float*)d_in[0];
    const int*   eidx  = (const int*)d_in[1];
    const float* c0_w1 = (const float*)d_in[2],  *c0_b1 = (const float*)d_in[3];
    const float* c0_w2 = (const float*)d_in[4],  *c0_b2 = (const float*)d_in[5];
    const float* c0_w3 = (const float*)d_in[6],  *c0_b3 = (const float*)d_in[7];
    const float* c1_w1 = (const float*)d_in[8],  *c1_b1 = (const float*)d_in[9];
    const float* c1_w2 = (const float*)d_in[10], *c1_b2 = (const float*)d_in[11];
    const float* c1_w3 = (const float*)d_in[12], *c1_b3 = (const float*)d_in[13];
    const float* f_w1  = (const float*)d_in[14], *f_b1  = (const float*)d_in[15];
    const float* f_w2  = (const float*)d_in[16], *f_b2  = (const float*)d_in[17];
    const int* src = eidx;
    const int* dst = eidx + NE;
    float* out = (float*)d_out;

    const size_t BUF = (size_t)NN * HID;
    uint* bA = (uint*)d_ws;
    uint* bB = bA + BUF;
    uint* bC = bB + BUF;
    int* row_ptr  = (int*)(bC + BUF);        // NN+1
    int* cnt      = row_ptr + (NN + 1);      // NN (fill cursor)
    int* esrc     = cnt + NN;                // NE
    int* partials = esrc + NE;               // SCAN_BLK
    uint* wp      = (uint*)(partials + SCAN_BLK);

    uint* p_c0w2 = wp + 0;          // 16384
    uint* p_c1w2 = wp + 16384;      // 16384
    uint* p_Wa   = wp + 32768;      // 32768 (c1_w1 · c0_w3)
    uint* p_Wb   = wp + 65536;      // 32768 (f_w1 · c1_w3)
    float* f_ba  = (float*)(wp + 98304);  // 128
    float* f_bb  = f_ba + 128;            // 128

    const int nb8 = (NN + 7) / 8;     // 5000 (K=11 embed)
    const int nbl = (NN + 31) / 32;   // 1250
    const int eb  = (NE + 255) / 256; // 2500

    // ---- weight prep (pack/swizzle + algebraic folds) + CSR build ----
    wprep_kernel<<<128, 256, 0, stream>>>(c0_w2, c1_w2, wp);
    wfold_kernel<<<128, 256, 0, stream>>>(c1_w1, c0_w3, c0_b3, c1_b1, p_Wa, f_ba);
    wfold_kernel<<<128, 256, 0, stream>>>(f_w1, c1_w3, c1_b3, f_b1, p_Wb, f_bb);
    (void)hipMemsetAsync(cnt, 0, NN * sizeof(int), stream);
    hist_kernel<<<eb, 256, 0, stream>>>(dst, cnt);
    scan1_kernel<<<SCAN_BLK, 256, 0, stream>>>(cnt, row_ptr, partials);
    scan2_kernel<<<1, 256, 0, stream>>>(partials, row_ptr);
    scan3_kernel<<<SCAN_BLK, 256, 0, stream>>>(row_ptr, partials);
    (void)hipMemsetAsync(cnt, 0, NN * sizeof(int), stream);
    fill_kernel<<<eb, 256, 0, stream>>>(src, dst, row_ptr, cnt, esrc);

    // ---- conv0 ----
    lin_kernel<11, true><<<nb8, 128, 0, stream>>>(x, c0_w1, c0_b1, bA, NN);       // h0
    fused_gather_lin_kernel<<<nbl, 256, 0, stream>>>(bA, row_ptr, esrc, p_c0w2, c0_b2, bB); // l1_0
    fused_gather_lin_kernel<<<nbl, 256, 0, stream>>>(bB, row_ptr, esrc, p_c0w2, c0_b2, bC); // l2_0
    // conv0.lin3 + conv1.lin1 folded: h1 = relu(Wa·cat(l1_0,l2_0) + ba)
    lin32_kernel<2, true><<<nbl, 256, 0, stream>>>(bB, bC, p_Wa, f_ba, bA);       // h1

    // ---- conv1 ----
    fused_gather_lin_kernel<<<nbl, 256, 0, stream>>>(bA, row_ptr, esrc, p_c1w2, c1_b2, bB); // l1_1
    fused_gather_lin_kernel<<<nbl, 256, 0, stream>>>(bB, row_ptr, esrc, p_c1w2, c1_b2, bC); // l2_1
    // conv1.lin3 + head.f_w1 folded + final dot fused:
    cat_head_kernel<<<nbl, 256, 0, stream>>>(bB, bC, p_Wb, f_bb, f_w2, f_b2, out);
}